// Round 1
// 814.336 us; speedup vs baseline: 1.0669x; 1.0669x over previous
//
#include <hip/hip_runtime.h>

#define N_NODES 100000
#define N_EDGES 1600000
#define D 128
#define NLAYER 3
#define NSLOT 8

// bucket sort params
#define NBKT 98          // ceil(100000 / 1024) node-buckets of 1024
#define EPB 4096         // edges per block in phase A
#define BCAP 96          // LDS per-bucket capacity (mean ~42/block)

typedef __bf16 bf16x8 __attribute__((ext_vector_type(8)));
typedef float f32x4 __attribute__((ext_vector_type(4)));

__device__ inline ushort f2b(float f) {
    union { float f; unsigned u; } v; v.f = f;
    unsigned u = v.u;
    return (ushort)((u + 0x7FFFu + ((u >> 16) & 1u)) >> 16);  // RNE
}
__device__ inline float b2f_lo(unsigned u) {
    union { unsigned u; float f; } v; v.u = u << 16; return v.f;
}
__device__ inline float b2f_hi(unsigned u) {
    union { unsigned u; float f; } v; v.u = u & 0xFFFF0000u; return v.f;
}

// ---------------------------------------------------------------- utility
__global__ void k_zero_i32(int* __restrict__ p, int n) {
    int i = blockIdx.x * blockDim.x + threadIdx.x;
    if (i < n) p[i] = 0;
}

// ---------------------------------------------------------------- CSR build
__global__ void k_hist(const int* __restrict__ dst, int* __restrict__ deg, int e) {
    int i = blockIdx.x * blockDim.x + threadIdx.x;
    if (i < e) atomicAdd(&deg[dst[i]], 1);
}

__global__ void k_scan_partial(const int* __restrict__ deg, int* __restrict__ bsum, int n) {
    __shared__ int sd[256];
    int tid  = threadIdx.x;
    int base = blockIdx.x * 1024 + tid * 4;
    int s = 0;
    #pragma unroll
    for (int j = 0; j < 4; ++j) {
        int idx = base + j;
        if (idx < n) s += deg[idx];
    }
    sd[tid] = s;
    __syncthreads();
    for (int o = 128; o > 0; o >>= 1) {
        if (tid < o) sd[tid] += sd[tid + o];
        __syncthreads();
    }
    if (tid == 0) bsum[blockIdx.x] = sd[0];
}

__global__ void k_scan_top(int* __restrict__ bsum, int nb) {
    __shared__ int sd[128];
    int tid = threadIdx.x;
    int v = (tid < nb) ? bsum[tid] : 0;
    sd[tid] = v;
    __syncthreads();
    int tot = v;
    for (int o = 1; o < 128; o <<= 1) {
        int t = (tid >= o) ? sd[tid - o] : 0;
        __syncthreads();
        sd[tid] += t;
        __syncthreads();
    }
    if (tid < nb) bsum[tid] = sd[tid] - tot;  // exclusive
}

__global__ void k_scan_final(const int* __restrict__ deg, const int* __restrict__ bofs,
                             int* __restrict__ offs, int* __restrict__ cursor,
                             int* __restrict__ bcur, int n) {
    __shared__ int sd[256];
    int tid  = threadIdx.x;
    int base = blockIdx.x * 1024 + tid * 4;
    int v[4];
    int s = 0;
    #pragma unroll
    for (int j = 0; j < 4; ++j) {
        int idx = base + j;
        v[j] = (idx < n) ? deg[idx] : 0;
        s += v[j];
    }
    sd[tid] = s;
    __syncthreads();
    int own = s;
    for (int o = 1; o < 256; o <<= 1) {
        int t = (tid >= o) ? sd[tid - o] : 0;
        __syncthreads();
        sd[tid] += t;
        __syncthreads();
    }
    int excl = sd[tid] - own + bofs[blockIdx.x];
    #pragma unroll
    for (int j = 0; j < 4; ++j) {
        int idx = base + j;
        if (idx < n) {
            offs[idx] = excl; cursor[idx] = excl;
            if ((idx & 1023) == 0) bcur[idx >> 10] = excl;  // bucket region start
        }
        excl += v[j];
    }
}

// ---------------------------------------------------------------- bucketed edge sort
// Phase A: stage packed (rel,src) per dst-bucket with contiguous global writes.
__global__ __launch_bounds__(256)
void k_bucket(const int* __restrict__ src, const int* __restrict__ dst,
              int* __restrict__ bcur, unsigned* __restrict__ staged, int e) {
    __shared__ unsigned lstage[NBKT * BCAP];
    __shared__ int lcur[NBKT];
    __shared__ int lbase[NBKT];
    int tid = threadIdx.x;
    for (int b = tid; b < NBKT; b += 256) lcur[b] = 0;
    __syncthreads();
    int base = blockIdx.x * EPB;
    for (int k = 0; k < EPB / 256; ++k) {
        int eid = base + k * 256 + tid;
        if (eid < e) {
            int d = dst[eid];
            int s = src[eid];
            int b = d >> 10;
            unsigned packed = ((unsigned)(d & 1023) << 17) | (unsigned)s;
            int p = atomicAdd(&lcur[b], 1);
            if (p < BCAP) {
                lstage[b * BCAP + p] = packed;
            } else {  // overflow fallback (statistically never: cap = 2.3x mean)
                int gp = atomicAdd(&bcur[b], 1);
                staged[gp] = packed;
            }
        }
    }
    __syncthreads();
    if (tid < NBKT) {
        int cnt = min(lcur[tid], BCAP);
        lbase[tid] = atomicAdd(&bcur[tid], cnt);
        lcur[tid] = cnt;
    }
    __syncthreads();
    int wave = tid >> 6, lane = tid & 63;
    for (int b = wave; b < NBKT; b += 4) {
        int cnt = lcur[b], gb = lbase[b];
        for (int j = lane; j < cnt; j += 64)
            staged[gb + j] = lstage[b * BCAP + j];
    }
}

// Phase B: within each bucket (1024 nodes, ~64KB csrc window), place edges at
// their final CSR slot. Writes stay inside one block's L2 working set.
__global__ __launch_bounds__(1024)
void k_place(const unsigned* __restrict__ staged, const int* __restrict__ offs,
             int* __restrict__ cursor, int* __restrict__ csrc) {
    int b = blockIdx.x;
    int start = offs[b << 10];
    int end = (b == NBKT - 1) ? N_EDGES : offs[(b + 1) << 10];
    int nodebase = b << 10;
    for (int i = start + blockIdx.y * 1024 + threadIdx.x; i < end; i += 2048) {
        unsigned p = staged[i];
        int s = (int)(p & 0x1FFFFu);
        int rel = (int)(p >> 17);
        int pos = atomicAdd(&cursor[nodebase + rel], 1);
        csrc[pos] = s;
    }
}

// ---------------------------------------------------------------- aggregation
// out[i,:] = bf16( h[i,:] + sum_j h[src_j,:] ).  One wave per node.
__global__ __launch_bounds__(256)
void k_agg_f32(const float* __restrict__ h, const int* __restrict__ offs,
               const int* __restrict__ deg, const int* __restrict__ csrc,
               unsigned* __restrict__ out, int n) {
    int node = blockIdx.x * 4 + (threadIdx.x >> 6);
    if (node >= n) return;
    int lane = threadIdx.x & 63;
    const float2* hp = (const float2*)h;
    float2 acc = hp[node * 64 + lane];
    int s = offs[node], d = deg[node];
    for (int c = 0; c < d; c += 64) {
        int m = min(64, d - c);
        int myi = (lane < m) ? csrc[s + c + lane] : 0;
        int j = 0;
        for (; j + 4 <= m; j += 4) {
            int n0 = __shfl(myi, j + 0), n1 = __shfl(myi, j + 1);
            int n2 = __shfl(myi, j + 2), n3 = __shfl(myi, j + 3);
            float2 v0 = hp[n0 * 64 + lane];
            float2 v1 = hp[n1 * 64 + lane];
            float2 v2 = hp[n2 * 64 + lane];
            float2 v3 = hp[n3 * 64 + lane];
            acc.x += v0.x + v1.x + v2.x + v3.x;
            acc.y += v0.y + v1.y + v2.y + v3.y;
        }
        for (; j < m; ++j) {
            int nb = __shfl(myi, j);
            float2 v = hp[nb * 64 + lane];
            acc.x += v.x; acc.y += v.y;
        }
    }
    out[node * 64 + lane] = (unsigned)f2b(acc.x) | ((unsigned)f2b(acc.y) << 16);
}

__global__ __launch_bounds__(256)
void k_agg_b16(const unsigned* __restrict__ h, const int* __restrict__ offs,
               const int* __restrict__ deg, const int* __restrict__ csrc,
               unsigned* __restrict__ out, int n) {
    int node = blockIdx.x * 4 + (threadIdx.x >> 6);
    if (node >= n) return;
    int lane = threadIdx.x & 63;
    unsigned u = h[node * 64 + lane];
    float ax = b2f_lo(u), ay = b2f_hi(u);
    int s = offs[node], d = deg[node];
    for (int c = 0; c < d; c += 64) {
        int m = min(64, d - c);
        int myi = (lane < m) ? csrc[s + c + lane] : 0;
        int j = 0;
        for (; j + 4 <= m; j += 4) {
            int n0 = __shfl(myi, j + 0), n1 = __shfl(myi, j + 1);
            int n2 = __shfl(myi, j + 2), n3 = __shfl(myi, j + 3);
            unsigned u0 = h[n0 * 64 + lane];
            unsigned u1 = h[n1 * 64 + lane];
            unsigned u2 = h[n2 * 64 + lane];
            unsigned u3 = h[n3 * 64 + lane];
            ax += b2f_lo(u0) + b2f_lo(u1) + b2f_lo(u2) + b2f_lo(u3);
            ay += b2f_hi(u0) + b2f_hi(u1) + b2f_hi(u2) + b2f_hi(u3);
        }
        for (; j < m; ++j) {
            int nb = __shfl(myi, j);
            unsigned uu = h[nb * 64 + lane];
            ax += b2f_lo(uu); ay += b2f_hi(uu);
        }
    }
    out[node * 64 + lane] = (unsigned)f2b(ax) | ((unsigned)f2b(ay) << 16);
}

// ---------------------------------------------------------------- weight prep
// W fp32 [3][k=128][n=128] -> Wt bf16 [3][n=128][k=128]
__global__ void k_wprep(const float* __restrict__ W, ushort* __restrict__ Wt) {
    int m = blockIdx.y, nn = blockIdx.x, k = threadIdx.x;
    float v = W[(m * D + k) * D + nn];
    Wt[(m * D + nn) * D + k] = f2b(v);
}

// ---------------------------------------------------------------- MFMA GEMM + fused BN stats
__device__ inline bf16x8 load_frag(const ushort* __restrict__ A, int row, int kb, int n,
                                   const float* __restrict__ ps, const float* __restrict__ psh) {
    bf16x8 r;
    if (row >= n) {
        #pragma unroll
        for (int j = 0; j < 8; ++j) r[j] = (__bf16)0.0f;
        return r;
    }
    if (!ps) return *(const bf16x8*)&A[(size_t)row * D + kb];
    unsigned u[4];
    *(uint4*)u = *(const uint4*)&A[(size_t)row * D + kb];
    #pragma unroll
    for (int p = 0; p < 4; ++p) {
        float lo = b2f_lo(u[p]) * ps[kb + 2 * p] + psh[kb + 2 * p];
        float hi = b2f_hi(u[p]) * ps[kb + 2 * p + 1] + psh[kb + 2 * p + 1];
        lo = lo > 0.f ? lo : 0.f;
        hi = hi > 0.f ? hi : 0.f;
        r[2 * p] = (__bf16)lo;
        r[2 * p + 1] = (__bf16)hi;
    }
    return r;
}

__global__ __launch_bounds__(256)
void k_gemm(const ushort* __restrict__ A, const ushort* __restrict__ Wt,
            const float* __restrict__ bias,
            const float* __restrict__ pre_scale, const float* __restrict__ pre_shift,
            ushort* __restrict__ C, float* __restrict__ stats, int n) {
    __shared__ ushort WtS[128 * 136];  // row stride 136 ushorts = 272 B (17x16B)

    // stage Wt (32 KB = 2048 uint4, 16 per row) coalesced
    const uint4* wsrc = (const uint4*)Wt;
    #pragma unroll
    for (int j = 0; j < 8; ++j) {
        int i = threadIdx.x + j * 256;   // 0..2047: row = i>>4, 16B-seg = i&15
        int r = i >> 4, s16 = i & 15;
        *(uint4*)&WtS[r * 136 + s16 * 8] = wsrc[i];
    }

    int wv   = threadIdx.x >> 6;
    int lane = threadIdx.x & 63;
    int m16  = lane & 15;
    int kq   = lane >> 4;
    int rowbase = blockIdx.x * 128 + wv * 32;

    // preload A-frags: 2 m-tiles x 4 k-steps
    bf16x8 a0[4], a1[4];
    #pragma unroll
    for (int ks = 0; ks < 4; ++ks) {
        int kb = ks * 32 + kq * 8;
        a0[ks] = load_frag(A, rowbase + m16, kb, n, pre_scale, pre_shift);
        a1[ks] = load_frag(A, rowbase + 16 + m16, kb, n, pre_scale, pre_shift);
    }

    f32x4 acc0[8], acc1[8];
    #pragma unroll
    for (int t = 0; t < 8; ++t) {
        acc0[t] = (f32x4){0.f, 0.f, 0.f, 0.f};
        acc1[t] = (f32x4){0.f, 0.f, 0.f, 0.f};
    }
    __syncthreads();

    #pragma unroll
    for (int ks = 0; ks < 4; ++ks) {
        #pragma unroll
        for (int t = 0; t < 8; ++t) {
            bf16x8 b = *(const bf16x8*)&WtS[(t * 16 + m16) * 136 + ks * 32 + kq * 8];
            acc0[t] = __builtin_amdgcn_mfma_f32_16x16x32_bf16(a0[ks], b, acc0[t], 0, 0, 0);
            acc1[t] = __builtin_amdgcn_mfma_f32_16x16x32_bf16(a1[ks], b, acc1[t], 0, 0, 0);
        }
    }

    // epilogue: bias, bf16 store, fused column stats
    int slot = blockIdx.x & (NSLOT - 1);
    #pragma unroll
    for (int t = 0; t < 8; ++t) {
        int col = t * 16 + m16;
        float bz = bias[col];
        float s = 0.f, q = 0.f;
        #pragma unroll
        for (int mt = 0; mt < 2; ++mt) {
            f32x4 v4 = mt ? acc1[t] : acc0[t];
            #pragma unroll
            for (int rr = 0; rr < 4; ++rr) {
                int row = rowbase + mt * 16 + kq * 4 + rr;
                if (row < n) {
                    float v = v4[rr] + bz;
                    C[(size_t)row * D + col] = f2b(v);
                    s += v; q += v * v;
                }
            }
        }
        s += __shfl_xor(s, 16); q += __shfl_xor(q, 16);
        s += __shfl_xor(s, 32); q += __shfl_xor(q, 32);
        if (kq == 0) {
            atomicAdd(&stats[slot * 256 + col], s);
            atomicAdd(&stats[slot * 256 + 128 + col], q);
        }
    }
}

// ---------------------------------------------------------------- BN param fold
// Also zeroes the stats slots for the next GEMM (replaces 5 k_zero launches).
__global__ void k_bnparams(float* __restrict__ stats, const float* __restrict__ gamma,
                           const float* __restrict__ beta, float* __restrict__ scale,
                           float* __restrict__ shift, float inv_n) {
    int c = threadIdx.x;  // 128 threads
    float s = 0.f, q = 0.f;
    for (int sl = 0; sl < NSLOT; ++sl) {
        s += stats[sl * 256 + c];
        q += stats[sl * 256 + 128 + c];
        stats[sl * 256 + c] = 0.f;
        stats[sl * 256 + 128 + c] = 0.f;
    }
    float mu  = s * inv_n;
    float var = q * inv_n - mu * mu;
    var = var < 0.f ? 0.f : var;
    float rs = rsqrtf(var + 1e-5f);
    float sc = gamma[c] * rs;
    scale[c] = sc;
    shift[c] = beta[c] - mu * sc;
}

// ---------------------------------------------------------------- BN apply (+relu)
// mode 0: bf16 out + relu;  mode 1: fp32 out, no relu (final layer)
__global__ __launch_bounds__(256)
void k_final(const unsigned* __restrict__ z, const float* __restrict__ scale,
             const float* __restrict__ shift, int mode,
             unsigned* __restrict__ outb, float* __restrict__ outf, int total2) {
    int i = blockIdx.x * 256 + threadIdx.x;  // index of uint2 = 4 bf16
    if (i >= total2) return;
    uint2 u = ((const uint2*)z)[i];
    int c = (i * 4) & (D - 1);
    float v0 = b2f_lo(u.x) * scale[c + 0] + shift[c + 0];
    float v1 = b2f_hi(u.x) * scale[c + 1] + shift[c + 1];
    float v2 = b2f_lo(u.y) * scale[c + 2] + shift[c + 2];
    float v3 = b2f_hi(u.y) * scale[c + 3] + shift[c + 3];
    if (mode == 0) {
        v0 = v0 > 0.f ? v0 : 0.f;
        v1 = v1 > 0.f ? v1 : 0.f;
        v2 = v2 > 0.f ? v2 : 0.f;
        v3 = v3 > 0.f ? v3 : 0.f;
        uint2 o;
        o.x = (unsigned)f2b(v0) | ((unsigned)f2b(v1) << 16);
        o.y = (unsigned)f2b(v2) | ((unsigned)f2b(v3) << 16);
        ((uint2*)outb)[i] = o;
    } else {
        float4 o;
        o.x = v0; o.y = v1; o.z = v2; o.w = v3;
        ((float4*)outf)[i] = o;
    }
}

// ---------------------------------------------------------------- launch
extern "C" void kernel_launch(void* const* d_in, const int* in_sizes, int n_in,
                              void* d_out, int out_size, void* d_ws, size_t ws_size,
                              hipStream_t stream) {
    const float* x   = (const float*)d_in[0];
    const int*   ei  = (const int*)d_in[1];
    const float* W1  = (const float*)d_in[4];
    const float* b1  = (const float*)d_in[5];
    const float* g1  = (const float*)d_in[6];
    const float* be1 = (const float*)d_in[7];
    const float* W2  = (const float*)d_in[8];
    const float* b2  = (const float*)d_in[9];
    const float* g2  = (const float*)d_in[10];
    const float* be2 = (const float*)d_in[11];

    const int* srcI = ei;             // edge_index[0]
    const int* dstI = ei + N_EDGES;   // edge_index[1]

    // workspace layout (~60 MB)
    char* ws = (char*)d_ws;
    unsigned* bufA = (unsigned*)ws; ws += (size_t)N_NODES * 64 * 4 + 65536;
    unsigned* bufB = (unsigned*)ws; ws += (size_t)N_NODES * 64 * 4 + 65536;
    int* csrc    = (int*)ws;   ws += (size_t)N_EDGES * 4;
    int* deg     = (int*)ws;   ws += (size_t)N_NODES * 4;
    int* offs    = (int*)ws;   ws += (size_t)N_NODES * 4;
    int* cursor  = (int*)ws;   ws += (size_t)N_NODES * 4;
    int* bsum    = (int*)ws;   ws += 512;
    int* bcur    = (int*)ws;   ws += 512;
    ushort* Wt1  = (ushort*)ws; ws += 3 * D * D * 2;
    ushort* Wt2  = (ushort*)ws; ws += 3 * D * D * 2;
    float* stats = (float*)ws; ws += NSLOT * 256 * 4;
    float* scale1 = (float*)ws; ws += 512;
    float* shift1 = (float*)ws; ws += 512;
    float* scale2 = (float*)ws; ws += 512;
    float* shift2 = (float*)ws; ws += 512;

    // staging buffer for bucketed edge sort: reuse bufB (dead until layer-0 GEMM)
    unsigned* staged = bufB;

    // ---- weight prep (fp32 -> transposed bf16) ----
    k_wprep<<<dim3(D, 3), D, 0, stream>>>(W1, Wt1);
    k_wprep<<<dim3(D, 3), D, 0, stream>>>(W2, Wt2);

    // ---- CSR build ----
    k_zero_i32<<<(N_NODES + 255) / 256, 256, 0, stream>>>(deg, N_NODES);
    k_hist<<<(N_EDGES + 255) / 256, 256, 0, stream>>>(dstI, deg, N_EDGES);
    int nsb = (N_NODES + 1023) / 1024;  // 98
    k_scan_partial<<<nsb, 256, 0, stream>>>(deg, bsum, N_NODES);
    k_scan_top<<<1, 128, 0, stream>>>(bsum, nsb);
    k_scan_final<<<nsb, 256, 0, stream>>>(deg, bsum, offs, cursor, bcur, N_NODES);
    // two-phase bucketed scatter (replaces k_scatter; kills 16x write amplification)
    k_bucket<<<(N_EDGES + EPB - 1) / EPB, 256, 0, stream>>>(srcI, dstI, bcur, staged, N_EDGES);
    k_place<<<dim3(NBKT, 2), 1024, 0, stream>>>(staged, offs, cursor, csrc);

    // stats zeroed once; k_bnparams re-zeroes after each read
    k_zero_i32<<<NSLOT, 256, 0, stream>>>((int*)stats, NSLOT * 256);

    const float inv_n = 1.0f / (float)N_NODES;
    int ngemm = (N_NODES + 127) / 128;  // 782
    int nfin  = (N_NODES * D / 4 + 255) / 256;

    for (int l = 0; l < NLAYER; ++l) {
        // agg: h -> bufA (bf16)
        if (l == 0)
            k_agg_f32<<<(N_NODES + 3) / 4, 256, 0, stream>>>(x, offs, deg, csrc, bufA, N_NODES);
        else
            k_agg_b16<<<(N_NODES + 3) / 4, 256, 0, stream>>>(bufB, offs, deg, csrc, bufA, N_NODES);
        // z1 = bufA @ W1 + b1  -> bufB (bf16), fused col stats
        k_gemm<<<ngemm, 256, 0, stream>>>(
            (const ushort*)bufA, Wt1 + (size_t)l * D * D, b1 + l * D,
            nullptr, nullptr, (ushort*)bufB, stats, N_NODES);
        k_bnparams<<<1, D, 0, stream>>>(stats, g1 + l * D, be1 + l * D, scale1, shift1, inv_n);
        // z2 = relu(bn1(z1)) @ W2 + b2 -> bufA (bf16), affine fused in A-frag load
        k_gemm<<<ngemm, 256, 0, stream>>>(
            (const ushort*)bufB, Wt2 + (size_t)l * D * D, b2 + l * D,
            scale1, shift1, (ushort*)bufA, stats, N_NODES);
        k_bnparams<<<1, D, 0, stream>>>(stats, g2 + l * D, be2 + l * D, scale2, shift2, inv_n);
        // h' = bn2(z2) (+relu except last): bufA -> bufB (bf16) or d_out (fp32)
        if (l < NLAYER - 1)
            k_final<<<nfin, 256, 0, stream>>>(bufA, scale2, shift2, 0, bufB, nullptr, N_NODES * D / 4);
        else
            k_final<<<nfin, 256, 0, stream>>>(bufA, scale2, shift2, 1, nullptr, (float*)d_out, N_NODES * D / 4);
    }
}

// Round 2
// 807.234 us; speedup vs baseline: 1.0762x; 1.0088x over previous
//
#include <hip/hip_runtime.h>

#define N_NODES 100000
#define N_EDGES 1600000
#define D 128
#define NLAYER 3
#define NSLOT 8

// bucket sort params
#define NBKT 98          // ceil(100000 / 1024) node-buckets of 1024
#define EPB 4096         // edges per block in phase A
#define BCAP 96          // LDS per-bucket capacity (mean ~42/block)

typedef __bf16 bf16x8 __attribute__((ext_vector_type(8)));
typedef float f32x4 __attribute__((ext_vector_type(4)));

__device__ inline ushort f2b(float f) {
    union { float f; unsigned u; } v; v.f = f;
    unsigned u = v.u;
    return (ushort)((u + 0x7FFFu + ((u >> 16) & 1u)) >> 16);  // RNE
}
__device__ inline float b2f_lo(unsigned u) {
    union { unsigned u; float f; } v; v.u = u << 16; return v.f;
}
__device__ inline float b2f_hi(unsigned u) {
    union { unsigned u; float f; } v; v.u = u & 0xFFFF0000u; return v.f;
}

// ---------------------------------------------------------------- utility
__global__ void k_zero_i32(int* __restrict__ p, int n) {
    int i = blockIdx.x * blockDim.x + threadIdx.x;
    if (i < n) p[i] = 0;
}

// ---------------------------------------------------------------- CSR build
__global__ void k_hist(const int* __restrict__ dst, int* __restrict__ deg, int e) {
    int i = blockIdx.x * blockDim.x + threadIdx.x;
    if (i < e) atomicAdd(&deg[dst[i]], 1);
}

__global__ void k_scan_partial(const int* __restrict__ deg, int* __restrict__ bsum, int n) {
    __shared__ int sd[256];
    int tid  = threadIdx.x;
    int base = blockIdx.x * 1024 + tid * 4;
    int s = 0;
    #pragma unroll
    for (int j = 0; j < 4; ++j) {
        int idx = base + j;
        if (idx < n) s += deg[idx];
    }
    sd[tid] = s;
    __syncthreads();
    for (int o = 128; o > 0; o >>= 1) {
        if (tid < o) sd[tid] += sd[tid + o];
        __syncthreads();
    }
    if (tid == 0) bsum[blockIdx.x] = sd[0];
}

__global__ void k_scan_top(int* __restrict__ bsum, int nb) {
    __shared__ int sd[128];
    int tid = threadIdx.x;
    int v = (tid < nb) ? bsum[tid] : 0;
    sd[tid] = v;
    __syncthreads();
    int tot = v;
    for (int o = 1; o < 128; o <<= 1) {
        int t = (tid >= o) ? sd[tid - o] : 0;
        __syncthreads();
        sd[tid] += t;
        __syncthreads();
    }
    if (tid < nb) bsum[tid] = sd[tid] - tot;  // exclusive
}

__global__ void k_scan_final(const int* __restrict__ deg, const int* __restrict__ bofs,
                             int* __restrict__ offs, int* __restrict__ cursor,
                             int* __restrict__ bcur, int n) {
    __shared__ int sd[256];
    int tid  = threadIdx.x;
    int base = blockIdx.x * 1024 + tid * 4;
    int v[4];
    int s = 0;
    #pragma unroll
    for (int j = 0; j < 4; ++j) {
        int idx = base + j;
        v[j] = (idx < n) ? deg[idx] : 0;
        s += v[j];
    }
    sd[tid] = s;
    __syncthreads();
    int own = s;
    for (int o = 1; o < 256; o <<= 1) {
        int t = (tid >= o) ? sd[tid - o] : 0;
        __syncthreads();
        sd[tid] += t;
        __syncthreads();
    }
    int excl = sd[tid] - own + bofs[blockIdx.x];
    #pragma unroll
    for (int j = 0; j < 4; ++j) {
        int idx = base + j;
        if (idx < n) {
            offs[idx] = excl; cursor[idx] = excl;
            if ((idx & 1023) == 0) bcur[idx >> 10] = excl;  // bucket region start
        }
        excl += v[j];
    }
}

// ---------------------------------------------------------------- bucketed edge sort
// Phase A: stage packed (rel,src) per dst-bucket with contiguous global writes.
__global__ __launch_bounds__(256)
void k_bucket(const int* __restrict__ src, const int* __restrict__ dst,
              int* __restrict__ bcur, unsigned* __restrict__ staged, int e) {
    __shared__ unsigned lstage[NBKT * BCAP];
    __shared__ int lcur[NBKT];
    __shared__ int lbase[NBKT];
    int tid = threadIdx.x;
    for (int b = tid; b < NBKT; b += 256) lcur[b] = 0;
    __syncthreads();
    int base = blockIdx.x * EPB;
    for (int k = 0; k < EPB / 256; ++k) {
        int eid = base + k * 256 + tid;
        if (eid < e) {
            int d = dst[eid];
            int s = src[eid];
            int b = d >> 10;
            unsigned packed = ((unsigned)(d & 1023) << 17) | (unsigned)s;
            int p = atomicAdd(&lcur[b], 1);
            if (p < BCAP) {
                lstage[b * BCAP + p] = packed;
            } else {  // overflow fallback (statistically never: cap = 2.3x mean)
                int gp = atomicAdd(&bcur[b], 1);
                staged[gp] = packed;
            }
        }
    }
    __syncthreads();
    if (tid < NBKT) {
        int cnt = min(lcur[tid], BCAP);
        lbase[tid] = atomicAdd(&bcur[tid], cnt);
        lcur[tid] = cnt;
    }
    __syncthreads();
    int wave = tid >> 6, lane = tid & 63;
    for (int b = wave; b < NBKT; b += 4) {
        int cnt = lcur[b], gb = lbase[b];
        for (int j = lane; j < cnt; j += 64)
            staged[gb + j] = lstage[b * BCAP + j];
    }
}

// Phase B: within each bucket (1024 nodes, ~64KB csrc window), place edges at
// their final CSR slot. Writes stay inside one block's L2 working set.
__global__ __launch_bounds__(1024)
void k_place(const unsigned* __restrict__ staged, const int* __restrict__ offs,
             int* __restrict__ cursor, int* __restrict__ csrc) {
    int b = blockIdx.x;
    int start = offs[b << 10];
    int end = (b == NBKT - 1) ? N_EDGES : offs[(b + 1) << 10];
    int nodebase = b << 10;
    for (int i = start + blockIdx.y * 1024 + threadIdx.x; i < end; i += 2048) {
        unsigned p = staged[i];
        int s = (int)(p & 0x1FFFFu);
        int rel = (int)(p >> 17);
        int pos = atomicAdd(&cursor[nodebase + rel], 1);
        csrc[pos] = s;
    }
}

// ---------------------------------------------------------------- aggregation
// out[i,:] = bf16( h[i,:] + sum_j h[src_j,:] ).  One wave per node.
// fp32 input: float4 loads, 32 lanes cover one 512B row -> 2 neighbors per
// load instruction (wave halves take even/odd neighbors), combined at end.
__global__ __launch_bounds__(256)
void k_agg_f32(const float* __restrict__ h, const int* __restrict__ offs,
               const int* __restrict__ deg, const int* __restrict__ csrc,
               unsigned* __restrict__ out, int n) {
    int node = blockIdx.x * 4 + (threadIdx.x >> 6);
    if (node >= n) return;
    int lane = threadIdx.x & 63;
    int half = lane >> 5;   // even/odd neighbor stream
    int sl   = lane & 31;   // covers cols 4sl..4sl+3
    const float4* hp = (const float4*)h;
    float ax = 0.f, ay = 0.f, az = 0.f, aw = 0.f;
    if (half == 0) {
        float4 v = hp[(size_t)node * 32 + sl];
        ax = v.x; ay = v.y; az = v.z; aw = v.w;
    }
    int s = offs[node], d = deg[node];
    for (int c = 0; c < d; c += 64) {
        int m = min(64, d - c);
        int myi = (lane < m) ? csrc[s + c + lane] : 0;
        int pairs = m >> 1;
        int p = 0;
        for (; p + 4 <= pairs; p += 4) {
            int n0 = __shfl(myi, 2 * p + 0 + half);
            int n1 = __shfl(myi, 2 * p + 2 + half);
            int n2 = __shfl(myi, 2 * p + 4 + half);
            int n3 = __shfl(myi, 2 * p + 6 + half);
            float4 v0 = hp[(size_t)n0 * 32 + sl];
            float4 v1 = hp[(size_t)n1 * 32 + sl];
            float4 v2 = hp[(size_t)n2 * 32 + sl];
            float4 v3 = hp[(size_t)n3 * 32 + sl];
            ax += v0.x + v1.x + v2.x + v3.x;
            ay += v0.y + v1.y + v2.y + v3.y;
            az += v0.z + v1.z + v2.z + v3.z;
            aw += v0.w + v1.w + v2.w + v3.w;
        }
        for (; p < pairs; ++p) {
            int nb = __shfl(myi, 2 * p + half);
            float4 v = hp[(size_t)nb * 32 + sl];
            ax += v.x; ay += v.y; az += v.z; aw += v.w;
        }
        if (m & 1) {  // odd tail: half 0 takes it
            int nb = __shfl(myi, m - 1);
            if (half == 0) {
                float4 v = hp[(size_t)nb * 32 + sl];
                ax += v.x; ay += v.y; az += v.z; aw += v.w;
            }
        }
    }
    ax += __shfl_xor(ax, 32);
    ay += __shfl_xor(ay, 32);
    az += __shfl_xor(az, 32);
    aw += __shfl_xor(aw, 32);
    if (half == 0) {
        uint2 o;
        o.x = (unsigned)f2b(ax) | ((unsigned)f2b(ay) << 16);
        o.y = (unsigned)f2b(az) | ((unsigned)f2b(aw) << 16);
        ((uint2*)out)[(size_t)node * 32 + sl] = o;
    }
}

// bf16 input: uint4 loads, 16 lanes cover one 256B row -> 4 neighbors per
// load instruction (wave quarters), combined with 2 shfl_xor steps.
__global__ __launch_bounds__(256)
void k_agg_b16(const unsigned* __restrict__ h, const int* __restrict__ offs,
               const int* __restrict__ deg, const int* __restrict__ csrc,
               unsigned* __restrict__ out, int n) {
    int node = blockIdx.x * 4 + (threadIdx.x >> 6);
    if (node >= n) return;
    int lane = threadIdx.x & 63;
    int q  = lane >> 4;   // neighbor stream j === q (mod 4)
    int sl = lane & 15;   // covers uints 4sl..4sl+3 (cols 8sl..8sl+7)
    const uint4* hp = (const uint4*)h;
    float a0 = 0.f, a1 = 0.f, a2 = 0.f, a3 = 0.f;
    float a4 = 0.f, a5 = 0.f, a6 = 0.f, a7 = 0.f;
    if (q == 0) {
        uint4 u = hp[(size_t)node * 16 + sl];
        a0 = b2f_lo(u.x); a1 = b2f_hi(u.x);
        a2 = b2f_lo(u.y); a3 = b2f_hi(u.y);
        a4 = b2f_lo(u.z); a5 = b2f_hi(u.z);
        a6 = b2f_lo(u.w); a7 = b2f_hi(u.w);
    }
    int s = offs[node], d = deg[node];
    for (int c = 0; c < d; c += 64) {
        int m = min(64, d - c);
        int myi = (lane < m) ? csrc[s + c + lane] : 0;
        int g4 = m >> 2;
        int g = 0;
        for (; g + 4 <= g4; g += 4) {
            int n0 = __shfl(myi, 4 * g + 0 + q);
            int n1 = __shfl(myi, 4 * g + 4 + q);
            int n2 = __shfl(myi, 4 * g + 8 + q);
            int n3 = __shfl(myi, 4 * g + 12 + q);
            uint4 u0 = hp[(size_t)n0 * 16 + sl];
            uint4 u1 = hp[(size_t)n1 * 16 + sl];
            uint4 u2 = hp[(size_t)n2 * 16 + sl];
            uint4 u3 = hp[(size_t)n3 * 16 + sl];
            a0 += b2f_lo(u0.x) + b2f_lo(u1.x) + b2f_lo(u2.x) + b2f_lo(u3.x);
            a1 += b2f_hi(u0.x) + b2f_hi(u1.x) + b2f_hi(u2.x) + b2f_hi(u3.x);
            a2 += b2f_lo(u0.y) + b2f_lo(u1.y) + b2f_lo(u2.y) + b2f_lo(u3.y);
            a3 += b2f_hi(u0.y) + b2f_hi(u1.y) + b2f_hi(u2.y) + b2f_hi(u3.y);
            a4 += b2f_lo(u0.z) + b2f_lo(u1.z) + b2f_lo(u2.z) + b2f_lo(u3.z);
            a5 += b2f_hi(u0.z) + b2f_hi(u1.z) + b2f_hi(u2.z) + b2f_hi(u3.z);
            a6 += b2f_lo(u0.w) + b2f_lo(u1.w) + b2f_lo(u2.w) + b2f_lo(u3.w);
            a7 += b2f_hi(u0.w) + b2f_hi(u1.w) + b2f_hi(u2.w) + b2f_hi(u3.w);
        }
        for (; g < g4; ++g) {
            int nb = __shfl(myi, 4 * g + q);
            uint4 u = hp[(size_t)nb * 16 + sl];
            a0 += b2f_lo(u.x); a1 += b2f_hi(u.x);
            a2 += b2f_lo(u.y); a3 += b2f_hi(u.y);
            a4 += b2f_lo(u.z); a5 += b2f_hi(u.z);
            a6 += b2f_lo(u.w); a7 += b2f_hi(u.w);
        }
        int rem = m & 3;
        if (rem) {
            int j = 4 * g4 + q;
            int nb = __shfl(myi, j < m ? j : 0);  // convergent shfl
            if (q < rem) {
                uint4 u = hp[(size_t)nb * 16 + sl];
                a0 += b2f_lo(u.x); a1 += b2f_hi(u.x);
                a2 += b2f_lo(u.y); a3 += b2f_hi(u.y);
                a4 += b2f_lo(u.z); a5 += b2f_hi(u.z);
                a6 += b2f_lo(u.w); a7 += b2f_hi(u.w);
            }
        }
    }
    a0 += __shfl_xor(a0, 16); a1 += __shfl_xor(a1, 16);
    a2 += __shfl_xor(a2, 16); a3 += __shfl_xor(a3, 16);
    a4 += __shfl_xor(a4, 16); a5 += __shfl_xor(a5, 16);
    a6 += __shfl_xor(a6, 16); a7 += __shfl_xor(a7, 16);
    a0 += __shfl_xor(a0, 32); a1 += __shfl_xor(a1, 32);
    a2 += __shfl_xor(a2, 32); a3 += __shfl_xor(a3, 32);
    a4 += __shfl_xor(a4, 32); a5 += __shfl_xor(a5, 32);
    a6 += __shfl_xor(a6, 32); a7 += __shfl_xor(a7, 32);
    if (q == 0) {
        uint4 o;
        o.x = (unsigned)f2b(a0) | ((unsigned)f2b(a1) << 16);
        o.y = (unsigned)f2b(a2) | ((unsigned)f2b(a3) << 16);
        o.z = (unsigned)f2b(a4) | ((unsigned)f2b(a5) << 16);
        o.w = (unsigned)f2b(a6) | ((unsigned)f2b(a7) << 16);
        ((uint4*)out)[(size_t)node * 16 + sl] = o;
    }
}

// ---------------------------------------------------------------- weight prep
// W fp32 [3][k=128][n=128] -> Wt bf16 [3][n=128][k=128]
__global__ void k_wprep(const float* __restrict__ W, ushort* __restrict__ Wt) {
    int m = blockIdx.y, nn = blockIdx.x, k = threadIdx.x;
    float v = W[(m * D + k) * D + nn];
    Wt[(m * D + nn) * D + k] = f2b(v);
}

// ---------------------------------------------------------------- MFMA GEMM + fused BN stats
__device__ inline bf16x8 load_frag(const ushort* __restrict__ A, int row, int kb, int n,
                                   const float* __restrict__ ps, const float* __restrict__ psh) {
    bf16x8 r;
    if (row >= n) {
        #pragma unroll
        for (int j = 0; j < 8; ++j) r[j] = (__bf16)0.0f;
        return r;
    }
    if (!ps) return *(const bf16x8*)&A[(size_t)row * D + kb];
    unsigned u[4];
    *(uint4*)u = *(const uint4*)&A[(size_t)row * D + kb];
    #pragma unroll
    for (int p = 0; p < 4; ++p) {
        float lo = b2f_lo(u[p]) * ps[kb + 2 * p] + psh[kb + 2 * p];
        float hi = b2f_hi(u[p]) * ps[kb + 2 * p + 1] + psh[kb + 2 * p + 1];
        lo = lo > 0.f ? lo : 0.f;
        hi = hi > 0.f ? hi : 0.f;
        r[2 * p] = (__bf16)lo;
        r[2 * p + 1] = (__bf16)hi;
    }
    return r;
}

__global__ __launch_bounds__(256)
void k_gemm(const ushort* __restrict__ A, const ushort* __restrict__ Wt,
            const float* __restrict__ bias,
            const float* __restrict__ pre_scale, const float* __restrict__ pre_shift,
            ushort* __restrict__ C, float* __restrict__ stats, int n) {
    __shared__ ushort WtS[128 * 136];  // row stride 136 ushorts = 272 B (17x16B)

    // stage Wt (32 KB = 2048 uint4, 16 per row) coalesced
    const uint4* wsrc = (const uint4*)Wt;
    #pragma unroll
    for (int j = 0; j < 8; ++j) {
        int i = threadIdx.x + j * 256;   // 0..2047: row = i>>4, 16B-seg = i&15
        int r = i >> 4, s16 = i & 15;
        *(uint4*)&WtS[r * 136 + s16 * 8] = wsrc[i];
    }

    int wv   = threadIdx.x >> 6;
    int lane = threadIdx.x & 63;
    int m16  = lane & 15;
    int kq   = lane >> 4;
    int rowbase = blockIdx.x * 128 + wv * 32;

    // preload A-frags: 2 m-tiles x 4 k-steps
    bf16x8 a0[4], a1[4];
    #pragma unroll
    for (int ks = 0; ks < 4; ++ks) {
        int kb = ks * 32 + kq * 8;
        a0[ks] = load_frag(A, rowbase + m16, kb, n, pre_scale, pre_shift);
        a1[ks] = load_frag(A, rowbase + 16 + m16, kb, n, pre_scale, pre_shift);
    }

    f32x4 acc0[8], acc1[8];
    #pragma unroll
    for (int t = 0; t < 8; ++t) {
        acc0[t] = (f32x4){0.f, 0.f, 0.f, 0.f};
        acc1[t] = (f32x4){0.f, 0.f, 0.f, 0.f};
    }
    __syncthreads();

    #pragma unroll
    for (int ks = 0; ks < 4; ++ks) {
        #pragma unroll
        for (int t = 0; t < 8; ++t) {
            bf16x8 b = *(const bf16x8*)&WtS[(t * 16 + m16) * 136 + ks * 32 + kq * 8];
            acc0[t] = __builtin_amdgcn_mfma_f32_16x16x32_bf16(a0[ks], b, acc0[t], 0, 0, 0);
            acc1[t] = __builtin_amdgcn_mfma_f32_16x16x32_bf16(a1[ks], b, acc1[t], 0, 0, 0);
        }
    }

    // epilogue: bias, bf16 store, fused column stats
    int slot = blockIdx.x & (NSLOT - 1);
    #pragma unroll
    for (int t = 0; t < 8; ++t) {
        int col = t * 16 + m16;
        float bz = bias[col];
        float s = 0.f, q = 0.f;
        #pragma unroll
        for (int mt = 0; mt < 2; ++mt) {
            f32x4 v4 = mt ? acc1[t] : acc0[t];
            #pragma unroll
            for (int rr = 0; rr < 4; ++rr) {
                int row = rowbase + mt * 16 + kq * 4 + rr;
                if (row < n) {
                    float v = v4[rr] + bz;
                    C[(size_t)row * D + col] = f2b(v);
                    s += v; q += v * v;
                }
            }
        }
        s += __shfl_xor(s, 16); q += __shfl_xor(q, 16);
        s += __shfl_xor(s, 32); q += __shfl_xor(q, 32);
        if (kq == 0) {
            atomicAdd(&stats[slot * 256 + col], s);
            atomicAdd(&stats[slot * 256 + 128 + col], q);
        }
    }
}

// ---------------------------------------------------------------- BN param fold
// Also zeroes the stats slots for the next GEMM (replaces 5 k_zero launches).
__global__ void k_bnparams(float* __restrict__ stats, const float* __restrict__ gamma,
                           const float* __restrict__ beta, float* __restrict__ scale,
                           float* __restrict__ shift, float inv_n) {
    int c = threadIdx.x;  // 128 threads
    float s = 0.f, q = 0.f;
    for (int sl = 0; sl < NSLOT; ++sl) {
        s += stats[sl * 256 + c];
        q += stats[sl * 256 + 128 + c];
        stats[sl * 256 + c] = 0.f;
        stats[sl * 256 + 128 + c] = 0.f;
    }
    float mu  = s * inv_n;
    float var = q * inv_n - mu * mu;
    var = var < 0.f ? 0.f : var;
    float rs = rsqrtf(var + 1e-5f);
    float sc = gamma[c] * rs;
    scale[c] = sc;
    shift[c] = beta[c] - mu * sc;
}

// ---------------------------------------------------------------- BN apply (+relu)
// mode 0: bf16 out + relu;  mode 1: fp32 out, no relu (final layer)
__global__ __launch_bounds__(256)
void k_final(const unsigned* __restrict__ z, const float* __restrict__ scale,
             const float* __restrict__ shift, int mode,
             unsigned* __restrict__ outb, float* __restrict__ outf, int total2) {
    int i = blockIdx.x * 256 + threadIdx.x;  // index of uint2 = 4 bf16
    if (i >= total2) return;
    uint2 u = ((const uint2*)z)[i];
    int c = (i * 4) & (D - 1);
    float v0 = b2f_lo(u.x) * scale[c + 0] + shift[c + 0];
    float v1 = b2f_hi(u.x) * scale[c + 1] + shift[c + 1];
    float v2 = b2f_lo(u.y) * scale[c + 2] + shift[c + 2];
    float v3 = b2f_hi(u.y) * scale[c + 3] + shift[c + 3];
    if (mode == 0) {
        v0 = v0 > 0.f ? v0 : 0.f;
        v1 = v1 > 0.f ? v1 : 0.f;
        v2 = v2 > 0.f ? v2 : 0.f;
        v3 = v3 > 0.f ? v3 : 0.f;
        uint2 o;
        o.x = (unsigned)f2b(v0) | ((unsigned)f2b(v1) << 16);
        o.y = (unsigned)f2b(v2) | ((unsigned)f2b(v3) << 16);
        ((uint2*)outb)[i] = o;
    } else {
        float4 o;
        o.x = v0; o.y = v1; o.z = v2; o.w = v3;
        ((float4*)outf)[i] = o;
    }
}

// ---------------------------------------------------------------- launch
extern "C" void kernel_launch(void* const* d_in, const int* in_sizes, int n_in,
                              void* d_out, int out_size, void* d_ws, size_t ws_size,
                              hipStream_t stream) {
    const float* x   = (const float*)d_in[0];
    const int*   ei  = (const int*)d_in[1];
    const float* W1  = (const float*)d_in[4];
    const float* b1  = (const float*)d_in[5];
    const float* g1  = (const float*)d_in[6];
    const float* be1 = (const float*)d_in[7];
    const float* W2  = (const float*)d_in[8];
    const float* b2  = (const float*)d_in[9];
    const float* g2  = (const float*)d_in[10];
    const float* be2 = (const float*)d_in[11];

    const int* srcI = ei;             // edge_index[0]
    const int* dstI = ei + N_EDGES;   // edge_index[1]

    // workspace layout (~60 MB)
    char* ws = (char*)d_ws;
    unsigned* bufA = (unsigned*)ws; ws += (size_t)N_NODES * 64 * 4 + 65536;
    unsigned* bufB = (unsigned*)ws; ws += (size_t)N_NODES * 64 * 4 + 65536;
    int* csrc    = (int*)ws;   ws += (size_t)N_EDGES * 4;
    int* deg     = (int*)ws;   ws += (size_t)N_NODES * 4;
    int* offs    = (int*)ws;   ws += (size_t)N_NODES * 4;
    int* cursor  = (int*)ws;   ws += (size_t)N_NODES * 4;
    int* bsum    = (int*)ws;   ws += 512;
    int* bcur    = (int*)ws;   ws += 512;
    ushort* Wt1  = (ushort*)ws; ws += 3 * D * D * 2;
    ushort* Wt2  = (ushort*)ws; ws += 3 * D * D * 2;
    float* stats = (float*)ws; ws += NSLOT * 256 * 4;
    float* scale1 = (float*)ws; ws += 512;
    float* shift1 = (float*)ws; ws += 512;
    float* scale2 = (float*)ws; ws += 512;
    float* shift2 = (float*)ws; ws += 512;

    // staging buffer for bucketed edge sort: reuse bufB (dead until layer-0 GEMM)
    unsigned* staged = bufB;

    // ---- weight prep (fp32 -> transposed bf16) ----
    k_wprep<<<dim3(D, 3), D, 0, stream>>>(W1, Wt1);
    k_wprep<<<dim3(D, 3), D, 0, stream>>>(W2, Wt2);

    // ---- CSR build ----
    k_zero_i32<<<(N_NODES + 255) / 256, 256, 0, stream>>>(deg, N_NODES);
    k_hist<<<(N_EDGES + 255) / 256, 256, 0, stream>>>(dstI, deg, N_EDGES);
    int nsb = (N_NODES + 1023) / 1024;  // 98
    k_scan_partial<<<nsb, 256, 0, stream>>>(deg, bsum, N_NODES);
    k_scan_top<<<1, 128, 0, stream>>>(bsum, nsb);
    k_scan_final<<<nsb, 256, 0, stream>>>(deg, bsum, offs, cursor, bcur, N_NODES);
    // two-phase bucketed scatter (replaces k_scatter; kills 16x write amplification)
    k_bucket<<<(N_EDGES + EPB - 1) / EPB, 256, 0, stream>>>(srcI, dstI, bcur, staged, N_EDGES);
    k_place<<<dim3(NBKT, 2), 1024, 0, stream>>>(staged, offs, cursor, csrc);

    // stats zeroed once; k_bnparams re-zeroes after each read
    k_zero_i32<<<NSLOT, 256, 0, stream>>>((int*)stats, NSLOT * 256);

    const float inv_n = 1.0f / (float)N_NODES;
    int ngemm = (N_NODES + 127) / 128;  // 782
    int nfin  = (N_NODES * D / 4 + 255) / 256;

    for (int l = 0; l < NLAYER; ++l) {
        // agg: h -> bufA (bf16)
        if (l == 0)
            k_agg_f32<<<(N_NODES + 3) / 4, 256, 0, stream>>>(x, offs, deg, csrc, bufA, N_NODES);
        else
            k_agg_b16<<<(N_NODES + 3) / 4, 256, 0, stream>>>(bufB, offs, deg, csrc, bufA, N_NODES);
        // z1 = bufA @ W1 + b1  -> bufB (bf16), fused col stats
        k_gemm<<<ngemm, 256, 0, stream>>>(
            (const ushort*)bufA, Wt1 + (size_t)l * D * D, b1 + l * D,
            nullptr, nullptr, (ushort*)bufB, stats, N_NODES);
        k_bnparams<<<1, D, 0, stream>>>(stats, g1 + l * D, be1 + l * D, scale1, shift1, inv_n);
        // z2 = relu(bn1(z1)) @ W2 + b2 -> bufA (bf16), affine fused in A-frag load
        k_gemm<<<ngemm, 256, 0, stream>>>(
            (const ushort*)bufB, Wt2 + (size_t)l * D * D, b2 + l * D,
            scale1, shift1, (ushort*)bufA, stats, N_NODES);
        k_bnparams<<<1, D, 0, stream>>>(stats, g2 + l * D, be2 + l * D, scale2, shift2, inv_n);
        // h' = bn2(z2) (+relu except last): bufA -> bufB (bf16) or d_out (fp32)
        if (l < NLAYER - 1)
            k_final<<<nfin, 256, 0, stream>>>(bufA, scale2, shift2, 0, bufB, nullptr, N_NODES * D / 4);
        else
            k_final<<<nfin, 256, 0, stream>>>(bufA, scale2, shift2, 1, nullptr, (float*)d_out, N_NODES * D / 4);
    }
}

// Round 3
// 770.476 us; speedup vs baseline: 1.1276x; 1.0477x over previous
//
#include <hip/hip_runtime.h>

#define N_NODES 100000
#define N_EDGES 1600000
#define D 128
#define NLAYER 3
#define NSLOT 8

// bucket sort params
#define NBKT 98          // ceil(100000 / 1024) node-buckets of 1024
#define EPB 4096         // edges per block in phase A
#define BCAP 96          // LDS per-bucket capacity (mean ~42/block)

typedef __bf16 bf16x8 __attribute__((ext_vector_type(8)));
typedef float f32x4 __attribute__((ext_vector_type(4)));

__device__ inline ushort f2b(float f) {
    union { float f; unsigned u; } v; v.f = f;
    unsigned u = v.u;
    return (ushort)((u + 0x7FFFu + ((u >> 16) & 1u)) >> 16);  // RNE
}
__device__ inline float b2f_lo(unsigned u) {
    union { unsigned u; float f; } v; v.u = u << 16; return v.f;
}
__device__ inline float b2f_hi(unsigned u) {
    union { unsigned u; float f; } v; v.u = u & 0xFFFF0000u; return v.f;
}

// ---------------------------------------------------------------- utility
__global__ void k_zero_i32(int* __restrict__ p, int n) {
    int i = blockIdx.x * blockDim.x + threadIdx.x;
    if (i < n) p[i] = 0;
}

// x fp32 -> packed bf16 (layer-0 agg input): halves layer-0 gather bytes
__global__ __launch_bounds__(256)
void k_x2b(const float* __restrict__ x, unsigned* __restrict__ out, int n4) {
    int i = blockIdx.x * 256 + threadIdx.x;  // float4 index
    if (i >= n4) return;
    float4 v = ((const float4*)x)[i];
    uint2 o;
    o.x = (unsigned)f2b(v.x) | ((unsigned)f2b(v.y) << 16);
    o.y = (unsigned)f2b(v.z) | ((unsigned)f2b(v.w) << 16);
    ((uint2*)out)[i] = o;
}

// ---------------------------------------------------------------- CSR build
__global__ void k_hist(const int* __restrict__ dst, int* __restrict__ deg, int e) {
    int i = blockIdx.x * blockDim.x + threadIdx.x;
    if (i < e) atomicAdd(&deg[dst[i]], 1);
}

__global__ void k_scan_partial(const int* __restrict__ deg, int* __restrict__ bsum, int n) {
    __shared__ int sd[256];
    int tid  = threadIdx.x;
    int base = blockIdx.x * 1024 + tid * 4;
    int s = 0;
    #pragma unroll
    for (int j = 0; j < 4; ++j) {
        int idx = base + j;
        if (idx < n) s += deg[idx];
    }
    sd[tid] = s;
    __syncthreads();
    for (int o = 128; o > 0; o >>= 1) {
        if (tid < o) sd[tid] += sd[tid + o];
        __syncthreads();
    }
    if (tid == 0) bsum[blockIdx.x] = sd[0];
}

__global__ void k_scan_top(int* __restrict__ bsum, int nb) {
    __shared__ int sd[128];
    int tid = threadIdx.x;
    int v = (tid < nb) ? bsum[tid] : 0;
    sd[tid] = v;
    __syncthreads();
    int tot = v;
    for (int o = 1; o < 128; o <<= 1) {
        int t = (tid >= o) ? sd[tid - o] : 0;
        __syncthreads();
        sd[tid] += t;
        __syncthreads();
    }
    if (tid < nb) bsum[tid] = sd[tid] - tot;  // exclusive
}

__global__ void k_scan_final(const int* __restrict__ deg, const int* __restrict__ bofs,
                             int* __restrict__ offs, int* __restrict__ cursor,
                             int* __restrict__ bcur, int n) {
    __shared__ int sd[256];
    int tid  = threadIdx.x;
    int base = blockIdx.x * 1024 + tid * 4;
    int v[4];
    int s = 0;
    #pragma unroll
    for (int j = 0; j < 4; ++j) {
        int idx = base + j;
        v[j] = (idx < n) ? deg[idx] : 0;
        s += v[j];
    }
    sd[tid] = s;
    __syncthreads();
    int own = s;
    for (int o = 1; o < 256; o <<= 1) {
        int t = (tid >= o) ? sd[tid - o] : 0;
        __syncthreads();
        sd[tid] += t;
        __syncthreads();
    }
    int excl = sd[tid] - own + bofs[blockIdx.x];
    #pragma unroll
    for (int j = 0; j < 4; ++j) {
        int idx = base + j;
        if (idx < n) {
            offs[idx] = excl; cursor[idx] = excl;
            if ((idx & 1023) == 0) bcur[idx >> 10] = excl;  // bucket region start
        }
        excl += v[j];
    }
}

// ---------------------------------------------------------------- bucketed edge sort
// Phase A: stage packed (rel,src) per dst-bucket with contiguous global writes.
__global__ __launch_bounds__(256)
void k_bucket(const int* __restrict__ src, const int* __restrict__ dst,
              int* __restrict__ bcur, unsigned* __restrict__ staged, int e) {
    __shared__ unsigned lstage[NBKT * BCAP];
    __shared__ int lcur[NBKT];
    __shared__ int lbase[NBKT];
    int tid = threadIdx.x;
    for (int b = tid; b < NBKT; b += 256) lcur[b] = 0;
    __syncthreads();
    int base = blockIdx.x * EPB;
    for (int k = 0; k < EPB / 256; ++k) {
        int eid = base + k * 256 + tid;
        if (eid < e) {
            int d = dst[eid];
            int s = src[eid];
            int b = d >> 10;
            unsigned packed = ((unsigned)(d & 1023) << 17) | (unsigned)s;
            int p = atomicAdd(&lcur[b], 1);
            if (p < BCAP) {
                lstage[b * BCAP + p] = packed;
            } else {  // overflow fallback (statistically never: cap = 2.3x mean)
                int gp = atomicAdd(&bcur[b], 1);
                staged[gp] = packed;
            }
        }
    }
    __syncthreads();
    if (tid < NBKT) {
        int cnt = min(lcur[tid], BCAP);
        lbase[tid] = atomicAdd(&bcur[tid], cnt);
        lcur[tid] = cnt;
    }
    __syncthreads();
    int wave = tid >> 6, lane = tid & 63;
    for (int b = wave; b < NBKT; b += 4) {
        int cnt = lcur[b], gb = lbase[b];
        for (int j = lane; j < cnt; j += 64)
            staged[gb + j] = lstage[b * BCAP + j];
    }
}

// Phase B: within each bucket (1024 nodes, ~64KB csrc window), place edges at
// their final CSR slot. Writes stay inside one block's L2 working set.
__global__ __launch_bounds__(1024)
void k_place(const unsigned* __restrict__ staged, const int* __restrict__ offs,
             int* __restrict__ cursor, int* __restrict__ csrc) {
    int b = blockIdx.x;
    int start = offs[b << 10];
    int end = (b == NBKT - 1) ? N_EDGES : offs[(b + 1) << 10];
    int nodebase = b << 10;
    for (int i = start + blockIdx.y * 1024 + threadIdx.x; i < end; i += 2048) {
        unsigned p = staged[i];
        int s = (int)(p & 0x1FFFFu);
        int rel = (int)(p >> 17);
        int pos = atomicAdd(&cursor[nodebase + rel], 1);
        csrc[pos] = s;
    }
}

// ---------------------------------------------------------------- aggregation
// out[i,:] = bf16( f(h[i,:]) + sum_j f(h[src_j,:]) ),  f = AFF ? relu(v*sc+sh) : v.
// One wave per node; uint4 loads, 16 lanes cover one 256B row -> 4 neighbors
// per load instruction (wave quarters), combined with 2 shfl_xor steps.
template <bool AFF>
__device__ inline void acc8(float* a, uint4 u, const float* sc, const float* sh) {
    float v[8];
    v[0] = b2f_lo(u.x); v[1] = b2f_hi(u.x);
    v[2] = b2f_lo(u.y); v[3] = b2f_hi(u.y);
    v[4] = b2f_lo(u.z); v[5] = b2f_hi(u.z);
    v[6] = b2f_lo(u.w); v[7] = b2f_hi(u.w);
    #pragma unroll
    for (int j = 0; j < 8; ++j) {
        float t = v[j];
        if (AFF) {
            t = t * sc[j] + sh[j];
            t = t > 0.f ? t : 0.f;
        }
        a[j] += t;
    }
}

template <bool AFF>
__global__ __launch_bounds__(256)
void k_agg(const unsigned* __restrict__ h, const int* __restrict__ offs,
           const int* __restrict__ deg, const int* __restrict__ csrc,
           const float* __restrict__ sc_, const float* __restrict__ sh_,
           unsigned* __restrict__ out, int n) {
    int node = blockIdx.x * 4 + (threadIdx.x >> 6);
    if (node >= n) return;
    int lane = threadIdx.x & 63;
    int q  = lane >> 4;   // neighbor stream j === q (mod 4)
    int sl = lane & 15;   // covers uints 4sl..4sl+3 (cols 8sl..8sl+7)
    const uint4* hp = (const uint4*)h;
    float sc[8], sh[8];
    if (AFF) {
        #pragma unroll
        for (int j = 0; j < 8; ++j) { sc[j] = sc_[sl * 8 + j]; sh[j] = sh_[sl * 8 + j]; }
    }
    float a[8];
    #pragma unroll
    for (int j = 0; j < 8; ++j) a[j] = 0.f;
    if (q == 0) acc8<AFF>(a, hp[(size_t)node * 16 + sl], sc, sh);
    int s = offs[node], d = deg[node];
    for (int c = 0; c < d; c += 64) {
        int m = min(64, d - c);
        int myi = (lane < m) ? csrc[s + c + lane] : 0;
        int g4 = m >> 2;
        int g = 0;
        for (; g + 4 <= g4; g += 4) {
            int n0 = __shfl(myi, 4 * g + 0 + q);
            int n1 = __shfl(myi, 4 * g + 4 + q);
            int n2 = __shfl(myi, 4 * g + 8 + q);
            int n3 = __shfl(myi, 4 * g + 12 + q);
            uint4 u0 = hp[(size_t)n0 * 16 + sl];
            uint4 u1 = hp[(size_t)n1 * 16 + sl];
            uint4 u2 = hp[(size_t)n2 * 16 + sl];
            uint4 u3 = hp[(size_t)n3 * 16 + sl];
            acc8<AFF>(a, u0, sc, sh);
            acc8<AFF>(a, u1, sc, sh);
            acc8<AFF>(a, u2, sc, sh);
            acc8<AFF>(a, u3, sc, sh);
        }
        for (; g < g4; ++g) {
            int nb = __shfl(myi, 4 * g + q);
            acc8<AFF>(a, hp[(size_t)nb * 16 + sl], sc, sh);
        }
        int rem = m & 3;
        if (rem) {
            int j = 4 * g4 + q;
            int nb = __shfl(myi, j < m ? j : 0);  // convergent shfl
            if (q < rem) acc8<AFF>(a, hp[(size_t)nb * 16 + sl], sc, sh);
        }
    }
    #pragma unroll
    for (int j = 0; j < 8; ++j) {
        a[j] += __shfl_xor(a[j], 16);
        a[j] += __shfl_xor(a[j], 32);
    }
    if (q == 0) {
        uint4 o;
        o.x = (unsigned)f2b(a[0]) | ((unsigned)f2b(a[1]) << 16);
        o.y = (unsigned)f2b(a[2]) | ((unsigned)f2b(a[3]) << 16);
        o.z = (unsigned)f2b(a[4]) | ((unsigned)f2b(a[5]) << 16);
        o.w = (unsigned)f2b(a[6]) | ((unsigned)f2b(a[7]) << 16);
        ((uint4*)out)[(size_t)node * 16 + sl] = o;
    }
}

// ---------------------------------------------------------------- weight prep
// W fp32 [3][k=128][n=128] -> Wt bf16 [3][n=128][k=128]
__global__ void k_wprep(const float* __restrict__ W, ushort* __restrict__ Wt) {
    int m = blockIdx.y, nn = blockIdx.x, k = threadIdx.x;
    float v = W[(m * D + k) * D + nn];
    Wt[(m * D + nn) * D + k] = f2b(v);
}

// ---------------------------------------------------------------- MFMA GEMM + fused BN stats
__device__ inline bf16x8 load_frag(const ushort* __restrict__ A, int row, int kb, int n,
                                   const float* __restrict__ ps, const float* __restrict__ psh) {
    bf16x8 r;
    if (row >= n) {
        #pragma unroll
        for (int j = 0; j < 8; ++j) r[j] = (__bf16)0.0f;
        return r;
    }
    if (!ps) return *(const bf16x8*)&A[(size_t)row * D + kb];
    unsigned u[4];
    *(uint4*)u = *(const uint4*)&A[(size_t)row * D + kb];
    #pragma unroll
    for (int p = 0; p < 4; ++p) {
        float lo = b2f_lo(u[p]) * ps[kb + 2 * p] + psh[kb + 2 * p];
        float hi = b2f_hi(u[p]) * ps[kb + 2 * p + 1] + psh[kb + 2 * p + 1];
        lo = lo > 0.f ? lo : 0.f;
        hi = hi > 0.f ? hi : 0.f;
        r[2 * p] = (__bf16)lo;
        r[2 * p + 1] = (__bf16)hi;
    }
    return r;
}

__global__ __launch_bounds__(256)
void k_gemm(const ushort* __restrict__ A, const ushort* __restrict__ Wt,
            const float* __restrict__ bias,
            const float* __restrict__ pre_scale, const float* __restrict__ pre_shift,
            ushort* __restrict__ C, float* __restrict__ stats, int n) {
    __shared__ ushort WtS[128 * 136];  // row stride 136 ushorts = 272 B (17x16B)

    // stage Wt (32 KB = 2048 uint4, 16 per row) coalesced
    const uint4* wsrc = (const uint4*)Wt;
    #pragma unroll
    for (int j = 0; j < 8; ++j) {
        int i = threadIdx.x + j * 256;   // 0..2047: row = i>>4, 16B-seg = i&15
        int r = i >> 4, s16 = i & 15;
        *(uint4*)&WtS[r * 136 + s16 * 8] = wsrc[i];
    }

    int wv   = threadIdx.x >> 6;
    int lane = threadIdx.x & 63;
    int m16  = lane & 15;
    int kq   = lane >> 4;
    int rowbase = blockIdx.x * 128 + wv * 32;

    // preload A-frags: 2 m-tiles x 4 k-steps
    bf16x8 a0[4], a1[4];
    #pragma unroll
    for (int ks = 0; ks < 4; ++ks) {
        int kb = ks * 32 + kq * 8;
        a0[ks] = load_frag(A, rowbase + m16, kb, n, pre_scale, pre_shift);
        a1[ks] = load_frag(A, rowbase + 16 + m16, kb, n, pre_scale, pre_shift);
    }

    f32x4 acc0[8], acc1[8];
    #pragma unroll
    for (int t = 0; t < 8; ++t) {
        acc0[t] = (f32x4){0.f, 0.f, 0.f, 0.f};
        acc1[t] = (f32x4){0.f, 0.f, 0.f, 0.f};
    }
    __syncthreads();

    #pragma unroll
    for (int ks = 0; ks < 4; ++ks) {
        #pragma unroll
        for (int t = 0; t < 8; ++t) {
            bf16x8 b = *(const bf16x8*)&WtS[(t * 16 + m16) * 136 + ks * 32 + kq * 8];
            acc0[t] = __builtin_amdgcn_mfma_f32_16x16x32_bf16(a0[ks], b, acc0[t], 0, 0, 0);
            acc1[t] = __builtin_amdgcn_mfma_f32_16x16x32_bf16(a1[ks], b, acc1[t], 0, 0, 0);
        }
    }

    // epilogue: bias, bf16 store, fused column stats
    int slot = blockIdx.x & (NSLOT - 1);
    #pragma unroll
    for (int t = 0; t < 8; ++t) {
        int col = t * 16 + m16;
        float bz = bias[col];
        float s = 0.f, q = 0.f;
        #pragma unroll
        for (int mt = 0; mt < 2; ++mt) {
            f32x4 v4 = mt ? acc1[t] : acc0[t];
            #pragma unroll
            for (int rr = 0; rr < 4; ++rr) {
                int row = rowbase + mt * 16 + kq * 4 + rr;
                if (row < n) {
                    float v = v4[rr] + bz;
                    C[(size_t)row * D + col] = f2b(v);
                    s += v; q += v * v;
                }
            }
        }
        s += __shfl_xor(s, 16); q += __shfl_xor(q, 16);
        s += __shfl_xor(s, 32); q += __shfl_xor(q, 32);
        if (kq == 0) {
            atomicAdd(&stats[slot * 256 + col], s);
            atomicAdd(&stats[slot * 256 + 128 + col], q);
        }
    }
}

// ---------------------------------------------------------------- BN param fold
// Also zeroes the stats slots for the next GEMM (replaces per-GEMM zeroing).
__global__ void k_bnparams(float* __restrict__ stats, const float* __restrict__ gamma,
                           const float* __restrict__ beta, float* __restrict__ scale,
                           float* __restrict__ shift, float inv_n) {
    int c = threadIdx.x;  // 128 threads
    float s = 0.f, q = 0.f;
    for (int sl = 0; sl < NSLOT; ++sl) {
        s += stats[sl * 256 + c];
        q += stats[sl * 256 + 128 + c];
        stats[sl * 256 + c] = 0.f;
        stats[sl * 256 + 128 + c] = 0.f;
    }
    float mu  = s * inv_n;
    float var = q * inv_n - mu * mu;
    var = var < 0.f ? 0.f : var;
    float rs = rsqrtf(var + 1e-5f);
    float sc = gamma[c] * rs;
    scale[c] = sc;
    shift[c] = beta[c] - mu * sc;
}

// ---------------------------------------------------------------- final BN apply (fp32 out)
__global__ __launch_bounds__(256)
void k_final(const unsigned* __restrict__ z, const float* __restrict__ scale,
             const float* __restrict__ shift, float* __restrict__ outf, int total2) {
    int i = blockIdx.x * 256 + threadIdx.x;  // index of uint2 = 4 bf16
    if (i >= total2) return;
    uint2 u = ((const uint2*)z)[i];
    int c = (i * 4) & (D - 1);
    float4 o;
    o.x = b2f_lo(u.x) * scale[c + 0] + shift[c + 0];
    o.y = b2f_hi(u.x) * scale[c + 1] + shift[c + 1];
    o.z = b2f_lo(u.y) * scale[c + 2] + shift[c + 2];
    o.w = b2f_hi(u.y) * scale[c + 3] + shift[c + 3];
    ((float4*)outf)[i] = o;
}

// ---------------------------------------------------------------- launch
extern "C" void kernel_launch(void* const* d_in, const int* in_sizes, int n_in,
                              void* d_out, int out_size, void* d_ws, size_t ws_size,
                              hipStream_t stream) {
    const float* x   = (const float*)d_in[0];
    const int*   ei  = (const int*)d_in[1];
    const float* W1  = (const float*)d_in[4];
    const float* b1  = (const float*)d_in[5];
    const float* g1  = (const float*)d_in[6];
    const float* be1 = (const float*)d_in[7];
    const float* W2  = (const float*)d_in[8];
    const float* b2  = (const float*)d_in[9];
    const float* g2  = (const float*)d_in[10];
    const float* be2 = (const float*)d_in[11];

    const int* srcI = ei;             // edge_index[0]
    const int* dstI = ei + N_EDGES;   // edge_index[1]

    // workspace layout (~60 MB)
    char* ws = (char*)d_ws;
    unsigned* bufA = (unsigned*)ws; ws += (size_t)N_NODES * 64 * 4 + 65536;
    unsigned* bufB = (unsigned*)ws; ws += (size_t)N_NODES * 64 * 4 + 65536;
    int* csrc    = (int*)ws;   ws += (size_t)N_EDGES * 4;
    int* deg     = (int*)ws;   ws += (size_t)N_NODES * 4;
    int* offs    = (int*)ws;   ws += (size_t)N_NODES * 4;
    int* cursor  = (int*)ws;   ws += (size_t)N_NODES * 4;
    int* bsum    = (int*)ws;   ws += 512;
    int* bcur    = (int*)ws;   ws += 512;
    ushort* Wt1  = (ushort*)ws; ws += 3 * D * D * 2;
    ushort* Wt2  = (ushort*)ws; ws += 3 * D * D * 2;
    float* stats = (float*)ws; ws += NSLOT * 256 * 4;
    float* scale1 = (float*)ws; ws += 512;
    float* shift1 = (float*)ws; ws += 512;
    float* scale2 = (float*)ws; ws += 512;
    float* shift2 = (float*)ws; ws += 512;

    // staging buffer for bucketed edge sort: reuse bufB (dead until layer-0 use)
    unsigned* staged = bufB;

    // ---- weight prep (fp32 -> transposed bf16) ----
    k_wprep<<<dim3(D, 3), D, 0, stream>>>(W1, Wt1);
    k_wprep<<<dim3(D, 3), D, 0, stream>>>(W2, Wt2);

    // ---- CSR build ----
    k_zero_i32<<<(N_NODES + 255) / 256, 256, 0, stream>>>(deg, N_NODES);
    k_hist<<<(N_EDGES + 255) / 256, 256, 0, stream>>>(dstI, deg, N_EDGES);
    int nsb = (N_NODES + 1023) / 1024;  // 98
    k_scan_partial<<<nsb, 256, 0, stream>>>(deg, bsum, N_NODES);
    k_scan_top<<<1, 128, 0, stream>>>(bsum, nsb);
    k_scan_final<<<nsb, 256, 0, stream>>>(deg, bsum, offs, cursor, bcur, N_NODES);
    // two-phase bucketed scatter (kills 16x write amplification of naive scatter)
    k_bucket<<<(N_EDGES + EPB - 1) / EPB, 256, 0, stream>>>(srcI, dstI, bcur, staged, N_EDGES);
    k_place<<<dim3(NBKT, 2), 1024, 0, stream>>>(staged, offs, cursor, csrc);

    // x -> bf16 into bufB (staged is dead now); halves layer-0 gather bytes
    k_x2b<<<(N_NODES * 32 + 255) / 256, 256, 0, stream>>>(x, bufB, N_NODES * 32);

    // stats zeroed once; k_bnparams re-zeroes after each read
    k_zero_i32<<<NSLOT, 256, 0, stream>>>((int*)stats, NSLOT * 256);

    const float inv_n = 1.0f / (float)N_NODES;
    int ngemm = (N_NODES + 127) / 128;  // 782
    int nagg  = (N_NODES + 3) / 4;
    int nfin  = (N_NODES * D / 4 + 255) / 256;

    // buffer ping-pong: cur = input to this layer's agg; alt = scratch
    unsigned* cur = bufB;
    unsigned* alt = bufA;

    for (int l = 0; l < NLAYER; ++l) {
        // agg: cur -> alt.  l>0: BN2-apply+relu of previous layer fused in.
        if (l == 0)
            k_agg<false><<<nagg, 256, 0, stream>>>(cur, offs, deg, csrc,
                                                   nullptr, nullptr, alt, N_NODES);
        else
            k_agg<true><<<nagg, 256, 0, stream>>>(cur, offs, deg, csrc,
                                                  scale2, shift2, alt, N_NODES);
        // z1 = alt @ W1 + b1 -> cur (bf16), fused col stats
        k_gemm<<<ngemm, 256, 0, stream>>>(
            (const ushort*)alt, Wt1 + (size_t)l * D * D, b1 + l * D,
            nullptr, nullptr, (ushort*)cur, stats, N_NODES);
        k_bnparams<<<1, D, 0, stream>>>(stats, g1 + l * D, be1 + l * D, scale1, shift1, inv_n);
        // z2 = relu(bn1(z1)) @ W2 + b2 -> alt (bf16), BN1 affine fused in A-frag load
        k_gemm<<<ngemm, 256, 0, stream>>>(
            (const ushort*)cur, Wt2 + (size_t)l * D * D, b2 + l * D,
            scale1, shift1, (ushort*)alt, stats, N_NODES);
        k_bnparams<<<1, D, 0, stream>>>(stats, g2 + l * D, be2 + l * D, scale2, shift2, inv_n);
        // z2 lives in alt; it is the next layer's agg input
        unsigned* t = cur; cur = alt; alt = t;
    }
    // final BN2 apply (no relu), fp32 out
    k_final<<<nfin, 256, 0, stream>>>(cur, scale2, shift2, (float*)d_out, N_NODES * D / 4);
}